// Round 10
// baseline (256.473 us; speedup 1.0000x reference)
//
#include <hip/hip_runtime.h>
#include <cstdint>

typedef unsigned short u16;
typedef __bf16 bf16x8 __attribute__((ext_vector_type(8)));
typedef float f32x4 __attribute__((ext_vector_type(4)));
typedef short s4 __attribute__((ext_vector_type(4)));

#define T_SEQ 2048
#define NH 16

// RTNE float -> bf16 bits
__device__ __forceinline__ u16 f2bf(float f) {
  union { float f; uint32_t u; } x; x.f = f;
  uint32_t r = (x.u + 0x7fffu + ((x.u >> 16) & 1u)) >> 16;
  return (u16)r;
}

// pack two floats -> two bf16 (RTNE)
__device__ __forceinline__ uint32_t pk2bf(float a, float b) {
  union { float f; uint32_t u; } x, y; x.f = a; y.f = b;
  uint32_t lo = (x.u + 0x7fffu + ((x.u >> 16) & 1u)) >> 16;
  uint32_t hi = (y.u + 0x7fffu + ((y.u >> 16) & 1u)) >> 16;
  return lo | (hi << 16);
}

// f32x4 accumulator quad -> 4 bf16
__device__ __forceinline__ s4 cvt4(f32x4 v) {
  union { __bf16 b[4]; s4 s; } u;
  u.b[0] = (__bf16)v[0]; u.b[1] = (__bf16)v[1];
  u.b[2] = (__bf16)v[2]; u.b[3] = (__bf16)v[3];
  return u.s;
}

__device__ __forceinline__ f32x4 mfma16(s4 a, s4 b, f32x4 c) {
#if __has_builtin(__builtin_amdgcn_mfma_f32_16x16x16bf16_1k)
  return __builtin_amdgcn_mfma_f32_16x16x16bf16_1k(a, b, c, 0, 0, 0);
#else
  asm("v_mfma_f32_16x16x16_bf16 %0, %1, %2, %0" : "+v"(c) : "v"(a), "v"(b));
  return c;
#endif
}

// native 2^x
__device__ __forceinline__ float exp2fast(float x) {
#if __has_builtin(__builtin_amdgcn_exp2f)
  return __builtin_amdgcn_exp2f(x);
#else
  float r; asm("v_exp_f32 %0, %1" : "=v"(r) : "v"(x)); return r;
#endif
}

// async 16B global -> LDS (HW scatters lane i at ldsbase + i*16)
__device__ __forceinline__ void gl_lds(const u16* g, u16* ldsbase) {
  __builtin_amdgcn_global_load_lds(
      (const __attribute__((address_space(1))) void*)g,
      (__attribute__((address_space(3))) void*)ldsbase, 16, 0, 0);
}

// C[M,N] = A[M,K] * W[N,K]^T.
// W is FP32 in global (w_qkv / w_o) -- converted to bf16 IN-REGISTER during
// staging (reg-stage: global fp32 -> pk2bf -> ds_write_b128).  A is fp32 (x,
// A_FP32=true, reg-staged the same way) or bf16 ws (ao, gl_lds direct).
// This fuses the old cvt_all kernel into the GEMMs: same RTNE rounding,
// minus 47 MB of HBM round-trip and one kernel launch.
// tile 128x128, BK=64, 512 threads = 8 waves (64x32 each) -> 16 waves/CU at
// the 64 KB dbuf LDS limit (2 blocks/CU).  XOR-swizzled LDS (both sides).
// 1 barrier/step: loads(t+1) issued early; compute(t); vmcnt(0); cvt+write;
// lgkmcnt(0); s_barrier.   KV epilogue: k cols -> qkv bf16 + outk fp32;
// v cols -> outv fp32 + transposed bf16 vt.  Bijective XCD swizzle.
template <bool CF32, bool KV, bool A_FP32>
__global__ __launch_bounds__(512) void gemm_bt(
    const void* __restrict__ Avp, const float* __restrict__ Wfp,
    void* __restrict__ Cp, float* __restrict__ outk, float* __restrict__ outv,
    u16* __restrict__ vtp, int M, int N, int K) {
  __shared__ __align__(16) u16 As[2][128 * 64];
  __shared__ __align__(16) u16 Bs[2][128 * 64];
  const int tid  = threadIdx.x;
  const int bid  = blockIdx.y * gridDim.x + blockIdx.x;
  const int per  = (gridDim.x * gridDim.y) >> 3;
  const int swz  = (bid & 7) * per + (bid >> 3);
  const int n0   = (swz % gridDim.x) * 128;
  const int m0   = (swz / gridDim.x) * 128;
  const int lane = tid & 63;
  const int wave = tid >> 6;            // 0..7
  const int wm   = (wave >> 2) * 64;    // 2 m-halves
  const int wn   = (wave & 3) * 32;     // 4 n-quarters
  const int l15  = lane & 15;
  const int quad = lane >> 4;
  // reg-staging coords: row wave*16 + lane>>2, chunks c0 and c0+4 (16B bf16)
  const int srw  = wave * 16 + (lane >> 2);
  const int c0   = lane & 3;
  // gl_lds coords (bf16 A): 8-row groups
  const int srow = lane >> 3;
  const int sc   = lane & 7;

  const float* Afp = (const float*)Avp;
  const u16*   Ab  = (const u16*)Avp;

  f32x4 acc[4][2];
#pragma unroll
  for (int i = 0; i < 4; i++)
#pragma unroll
    for (int j = 0; j < 2; j++) acc[i][j] = (f32x4){0.f, 0.f, 0.f, 0.f};

  float4 ra[4], rw[4];  // in-flight fp32 staging regs

  auto loadW = [&](int k0) {
    const float* src = &Wfp[(size_t)(n0 + srw) * K + k0];
    const int g0 = ((c0)     ^ (srw & 7)) * 8;   // pre-swizzled source col
    const int g1 = ((c0 + 4) ^ (srw & 7)) * 8;
    rw[0] = *(const float4*)(src + g0);
    rw[1] = *(const float4*)(src + g0 + 4);
    rw[2] = *(const float4*)(src + g1);
    rw[3] = *(const float4*)(src + g1 + 4);
  };
  auto writeW = [&](int d) {
    uint4 o;
    o.x = pk2bf(rw[0].x, rw[0].y); o.y = pk2bf(rw[0].z, rw[0].w);
    o.z = pk2bf(rw[1].x, rw[1].y); o.w = pk2bf(rw[1].z, rw[1].w);
    *(uint4*)&Bs[d][srw * 64 + c0 * 8] = o;
    o.x = pk2bf(rw[2].x, rw[2].y); o.y = pk2bf(rw[2].z, rw[2].w);
    o.z = pk2bf(rw[3].x, rw[3].y); o.w = pk2bf(rw[3].z, rw[3].w);
    *(uint4*)&Bs[d][srw * 64 + (c0 + 4) * 8] = o;
  };
  auto loadA = [&](int d, int k0) {
    if constexpr (A_FP32) {
      const float* src = &Afp[(size_t)(m0 + srw) * K + k0];
      const int g0 = ((c0)     ^ (srw & 7)) * 8;
      const int g1 = ((c0 + 4) ^ (srw & 7)) * 8;
      ra[0] = *(const float4*)(src + g0);
      ra[1] = *(const float4*)(src + g0 + 4);
      ra[2] = *(const float4*)(src + g1);
      ra[3] = *(const float4*)(src + g1 + 4);
    } else {
#pragma unroll
      for (int i = 0; i < 2; i++) {
        int r0  = (i * 8 + wave) * 8;
        int row = r0 + srow;
        int gc  = (sc ^ (row & 7)) << 3;
        gl_lds(&Ab[(size_t)(m0 + row) * K + k0 + gc], &As[d][r0 * 64]);
      }
    }
  };
  auto writeA = [&](int d) {
    if constexpr (A_FP32) {
      uint4 o;
      o.x = pk2bf(ra[0].x, ra[0].y); o.y = pk2bf(ra[0].z, ra[0].w);
      o.z = pk2bf(ra[1].x, ra[1].y); o.w = pk2bf(ra[1].z, ra[1].w);
      *(uint4*)&As[d][srw * 64 + c0 * 8] = o;
      o.x = pk2bf(ra[2].x, ra[2].y); o.y = pk2bf(ra[2].z, ra[2].w);
      o.z = pk2bf(ra[3].x, ra[3].y); o.w = pk2bf(ra[3].z, ra[3].w);
      *(uint4*)&As[d][srw * 64 + (c0 + 4) * 8] = o;
    }
  };

  // prologue: stage tile 0 into buf 0
  loadA(0, 0); loadW(0);
  asm volatile("s_waitcnt vmcnt(0)" ::: "memory");
  __builtin_amdgcn_sched_barrier(0);
  writeA(0); writeW(0);
  asm volatile("s_waitcnt lgkmcnt(0)" ::: "memory");
  __builtin_amdgcn_sched_barrier(0);
  __builtin_amdgcn_s_barrier();
  __builtin_amdgcn_sched_barrier(0);

  const int NT = K >> 6;
  int cur = 0;
  for (int t = 0; t < NT; t++) {
    if (t + 1 < NT) { loadA(cur ^ 1, (t + 1) * 64); loadW((t + 1) * 64); }
    // compute tile t from buf[cur] (swizzled reads)
#pragma unroll
    for (int kk = 0; kk < 64; kk += 32) {
      bf16x8 af[4], bfr[2];
#pragma unroll
      for (int i = 0; i < 4; i++) {
        int arow = wm + i * 16 + l15;
        af[i] = *(const bf16x8*)((const char*)&As[cur][0] + arow * 128 +
                                 ((((kk >> 3) + quad) ^ (arow & 7)) << 4));
      }
#pragma unroll
      for (int j = 0; j < 2; j++) {
        int brow = wn + j * 16 + l15;
        bfr[j] = *(const bf16x8*)((const char*)&Bs[cur][0] + brow * 128 +
                                  ((((kk >> 3) + quad) ^ (brow & 7)) << 4));
      }
#pragma unroll
      for (int i = 0; i < 4; i++)
#pragma unroll
        for (int j = 0; j < 2; j++)
          acc[i][j] = __builtin_amdgcn_mfma_f32_16x16x32_bf16(af[i], bfr[j], acc[i][j], 0, 0, 0);
    }
    if (t + 1 < NT) {
      asm volatile("s_waitcnt vmcnt(0)" ::: "memory");   // fp32 regs + gl_lds
      __builtin_amdgcn_sched_barrier(0);
      writeA(cur ^ 1); writeW(cur ^ 1);
    }
    asm volatile("s_waitcnt lgkmcnt(0)" ::: "memory");   // my ds_writes landed
    __builtin_amdgcn_sched_barrier(0);
    __builtin_amdgcn_s_barrier();
    __builtin_amdgcn_sched_barrier(0);
    cur ^= 1;
  }

#pragma unroll
  for (int i = 0; i < 4; i++)
#pragma unroll
    for (int j = 0; j < 2; j++) {
      const int row0 = m0 + wm + i * 16 + quad * 4;  // 4 consecutive rows
      const int col  = n0 + wn + j * 16 + l15;
      if constexpr (CF32) {
#pragma unroll
        for (int r = 0; r < 4; r++)
          ((float*)Cp)[(size_t)(row0 + r) * N + col] = acc[i][j][r];
      } else if (KV && col >= 2048) {
        // v: fp32 output + transposed bf16 into vt (4 consecutive t -> 8B)
        const int hd = col - 2048;
        const int b_ = row0 >> 11, t_ = row0 & 2047;
        uint2 pk;
        pk.x = pk2bf(acc[i][j][0], acc[i][j][1]);
        pk.y = pk2bf(acc[i][j][2], acc[i][j][3]);
        *(uint2*)&vtp[((size_t)(b_ * NH + (hd >> 6)) * 64 + (hd & 63)) * 2048 + t_] = pk;
#pragma unroll
        for (int r = 0; r < 4; r++)
          outv[(size_t)(row0 + r) * 1024 + hd] = acc[i][j][r];
      } else {
#pragma unroll
        for (int r = 0; r < 4; r++) {
          float v = acc[i][j][r];
          ((u16*)Cp)[(size_t)(row0 + r) * N + col] = f2bf(v);
          if constexpr (KV) {
            if (col >= 1024) outk[(size_t)(row0 + r) * 1024 + (col - 1024)] = v;
          }
        }
      }
    }
}

// Flash-style causal attention, swapped QK^T (S^T = mfma(K,Q)).
// ONE 64-row q-tile per block (grid 32x32 = 1024 blocks -> 4 blocks/CU).
// 2-buffer K/V LDS pipeline (32 KB/block), one barrier/step, stage(s+1)
// issued right after the barrier.  Constant-sum balanced, per-head bijective
// q-tile assignment: co-resident quads {by, by+8, by+16, by+24} sum to 66.
// (Round-9 winner, 56.4 us, unchanged.)
__global__ __launch_bounds__(256) void attn(const u16* __restrict__ qkv,
                                            const u16* __restrict__ vt,
                                            u16* __restrict__ o) {
  __shared__ __align__(16) u16 Ks[2][64 * 64];
  __shared__ __align__(16) u16 Vts[2][64 * 64];

  const int tid  = threadIdx.x;
  const int bx   = blockIdx.x;          // 0..31
  const int by   = blockIdx.y;          // bh = b*16+h, 0..31
  const int b    = by >> 4, h = by & 15;
  const int lane = tid & 63, wave = tid >> 6;
  const int l15  = lane & 15, quad = lane >> 4;
  const int srow = lane >> 3, sc = lane & 7;
  const size_t qbase = (size_t)b * T_SEQ * 3072;
  const size_t vbase = (size_t)(b * NH + h) * 64 * 2048;
  const float C = 0.1803368801f;        // 0.125 * log2(e)

  // constant-sum balanced, per-head bijective q-tile assignment
  const int u  = (bx + (by & 7) * 5) & 31;
  const int c  = by >> 3;               // 0..3: co-resident quad index
  const int v_ = (u + ((c >> 1) << 4)) & 31;
  const int qt = (c & 1) ? (31 - v_) : v_;
  const int steps = qt + 1;

  const int wq0  = qt * 64 + wave * 16;
  const int qrow = wq0 + l15;

  // Q fragments (B-operand: n=l15 -> q row), loaded once from global
  const u16* qp = &qkv[qbase + (size_t)qrow * 3072 + h * 64];
  const bf16x8 qf0 = *(const bf16x8*)&qp[quad * 8];
  const bf16x8 qf1 = *(const bf16x8*)&qp[32 + quad * 8];

  f32x4 acc_o[4];
#pragma unroll
  for (int n = 0; n < 4; n++) acc_o[n] = (f32x4){0.f, 0.f, 0.f, 0.f};
  float m2run = -1e30f, lrun = 0.f;

  // async stage of k-tile kt into buffer buf: 4 gl_lds per wave
  auto stage = [&](int buf, int kt) {
    const int k0 = kt * 64;
#pragma unroll
    for (int i = 0; i < 2; i++) {
      int r0  = (wave * 2 + i) * 8;
      int row = r0 + srow;
      int gc  = (sc ^ (row & 7)) << 3;
      gl_lds(&qkv[qbase + (size_t)(k0 + row) * 3072 + 1024 + h * 64 + gc], &Ks[buf][r0 * 64]);
      gl_lds(&vt[vbase + (size_t)row * 2048 + k0 + gc], &Vts[buf][r0 * 64]);
    }
  };

  stage(0, 0);

  for (int s = 0; s < steps; s++) {
    const int cur = s & 1;
    asm volatile("s_waitcnt vmcnt(0)" ::: "memory");
    __builtin_amdgcn_s_barrier();
    __builtin_amdgcn_sched_barrier(0);

    if (s + 1 < steps) stage(cur ^ 1, s + 1);

    const int k0 = s * 64;

    // S^T[j]: row (quad*4+r) = k_local, col l15 = q  (swizzled Ks reads)
    f32x4 sacc[4];
#pragma unroll
    for (int j = 0; j < 4; j++) sacc[j] = (f32x4){0.f, 0.f, 0.f, 0.f};
    __builtin_amdgcn_s_setprio(1);
#pragma unroll
    for (int j = 0; j < 4; j++) {
      int krow = j * 16 + l15;
      const char* kb = (const char*)&Ks[cur][0] + krow * 128;
      bf16x8 kfa = *(const bf16x8*)(kb + ((quad ^ (krow & 7)) << 4));
      bf16x8 kfb = *(const bf16x8*)(kb + (((4 + quad) ^ (krow & 7)) << 4));
      sacc[j] = __builtin_amdgcn_mfma_f32_16x16x32_bf16(kfa, qf0, sacc[j], 0, 0, 0);
      sacc[j] = __builtin_amdgcn_mfma_f32_16x16x32_bf16(kfb, qf1, sacc[j], 0, 0, 0);
    }
    __builtin_amdgcn_s_setprio(0);

    if (s == qt) {  // diagonal tile: causal mask on raw scores
#pragma unroll
      for (int j = 0; j < 4; j++)
#pragma unroll
        for (int r = 0; r < 4; r++) {
          int k = k0 + j * 16 + quad * 4 + r;
          if (k > qrow) sacc[j][r] = -1e30f;
        }
    }

    // row max, tree-shaped
    float mj[4];
#pragma unroll
    for (int j = 0; j < 4; j++)
      mj[j] = fmaxf(fmaxf(sacc[j][0], sacc[j][1]), fmaxf(sacc[j][2], sacc[j][3]));
    float mx = fmaxf(fmaxf(mj[0], mj[1]), fmaxf(mj[2], mj[3]));
    mx = fmaxf(mx, __shfl_xor(mx, 16));
    mx = fmaxf(mx, __shfl_xor(mx, 32));
    const float m2x = mx * C;

    // defer-max: only rescale when the max grew by > 8 (log2 domain)
    if (!__all(m2x <= m2run + 8.0f)) {
      const float m2new = fmaxf(m2run, m2x);
      const float alpha = exp2fast(m2run - m2new);
      lrun *= alpha;
      m2run = m2new;
#pragma unroll
      for (int r = 0; r < 4; r++) {
        float ar = __shfl(alpha, quad * 4 + r);
#pragma unroll
        for (int n = 0; n < 4; n++) acc_o[n][r] *= ar;
      }
    }

    // p = exp2(s*C - m2run); tree sum
    const float nm = m2run;
    float ts[4];
#pragma unroll
    for (int j = 0; j < 4; j++) {
#pragma unroll
      for (int r = 0; r < 4; r++) sacc[j][r] = exp2fast(fmaf(sacc[j][r], C, -nm));
      ts[j] = (sacc[j][0] + sacc[j][1]) + (sacc[j][2] + sacc[j][3]);
    }
    float sum = (ts[0] + ts[1]) + (ts[2] + ts[3]);
    sum += __shfl_xor(sum, 16);
    sum += __shfl_xor(sum, 32);
    lrun += sum;

    // P -> bf16 A-frags (m=l15 -> q, k = quad*4+e), in-register
    s4 pa[4];
#pragma unroll
    for (int j = 0; j < 4; j++) pa[j] = cvt4(sacc[j]);

    // PV: B-frag = V^T[d = n*16+l15][k0 + j*16+quad*4 ..+3], swizzled b64
    __builtin_amdgcn_s_setprio(1);
#pragma unroll
    for (int j = 0; j < 4; j++)
#pragma unroll
      for (int n = 0; n < 4; n++) {
        int vrow = n * 16 + l15;
        int ch = (j * 2 + (quad >> 1)) ^ (vrow & 7);
        const s4 vf = *(const s4*)((const char*)&Vts[cur][0] + vrow * 128 +
                                   (ch << 4) + ((quad & 1) << 3));
        acc_o[n] = mfma16(pa[j], vf, acc_o[n]);
      }
    __builtin_amdgcn_s_setprio(0);
  }

  const float linv = 1.0f / lrun;
#pragma unroll
  for (int r = 0; r < 4; r++) {
    const float lr = __shfl(linv, quad * 4 + r);
    const int row = wq0 + quad * 4 + r;
#pragma unroll
    for (int n = 0; n < 4; n++)
      o[(size_t)(b * T_SEQ + row) * 1024 + h * 64 + n * 16 + l15] =
          f2bf(acc_o[n][r] * lr);
  }
}

extern "C" void kernel_launch(void* const* d_in, const int* in_sizes, int n_in,
                              void* d_out, int out_size, void* d_ws, size_t ws_size,
                              hipStream_t stream) {
  const float* x     = (const float*)d_in[0];   // (2,2048,1024) fp32
  const float* w_qkv = (const float*)d_in[1];   // (3072,1024)   fp32
  const float* w_o   = (const float*)d_in[2];   // (1024,1024)   fp32
  float* out  = (float*)d_out;                  // fp32 (4096,1024)
  float* outk = out + (size_t)4194304;
  float* outv = out + (size_t)8388608;

  u16* qkv = (u16*)d_ws;                        // 4096*3072
  u16* vt  = qkv + (size_t)4096 * 3072;         // 32*64*2048
  u16* ao  = vt  + (size_t)4194304;             // 4096*1024

  // 1. qkv(bf16 ws) = x @ w_qkv^T with FUSED fp32->bf16 conversion of both
  //    operands in staging; k -> qkv+outk; v -> outv + vt (fused transpose)
  gemm_bt<false, true, true><<<dim3(24, 32), 512, 0, stream>>>(
      x, w_qkv, qkv, outk, outv, vt, 4096, 3072, 1024);
  // 2. flash attention -> ao (bf16 ws): 1 tile/block, 1024 blocks, 2-buf pipe
  attn<<<dim3(32, 32), 256, 0, stream>>>(qkv, vt, ao);
  // 3. out(fp32) = ao @ w_o^T: A via gl_lds (bf16 ws), w_o fp32 reg-staged
  gemm_bt<true, false, false><<<dim3(8, 32), 512, 0, stream>>>(
      ao, w_o, out, nullptr, nullptr, nullptr, 4096, 1024, 1024);
}

// Round 11
// 195.874 us; speedup vs baseline: 1.3094x; 1.3094x over previous
//
#include <hip/hip_runtime.h>
#include <cstdint>

typedef unsigned short u16;
typedef __bf16 bf16x8 __attribute__((ext_vector_type(8)));
typedef float f32x4 __attribute__((ext_vector_type(4)));
typedef short s4 __attribute__((ext_vector_type(4)));

#define T_SEQ 2048
#define NH 16

// RTNE float -> bf16 bits
__device__ __forceinline__ u16 f2bf(float f) {
  union { float f; uint32_t u; } x; x.f = f;
  uint32_t r = (x.u + 0x7fffu + ((x.u >> 16) & 1u)) >> 16;
  return (u16)r;
}

// pack two floats -> two bf16 (RTNE)
__device__ __forceinline__ uint32_t pk2bf(float a, float b) {
  union { float f; uint32_t u; } x, y; x.f = a; y.f = b;
  uint32_t lo = (x.u + 0x7fffu + ((x.u >> 16) & 1u)) >> 16;
  uint32_t hi = (y.u + 0x7fffu + ((y.u >> 16) & 1u)) >> 16;
  return lo | (hi << 16);
}

// 8 fp32 -> 8 bf16 (one uint4 store)
__device__ __forceinline__ void cvt8(u16* dst, const float* src) {
  float4 a = *(const float4*)src;
  float4 b = *(const float4*)(src + 4);
  uint4 o;
  o.x = pk2bf(a.x, a.y); o.y = pk2bf(a.z, a.w);
  o.z = pk2bf(b.x, b.y); o.w = pk2bf(b.z, b.w);
  *(uint4*)dst = o;
}

// fused fp32 -> bf16 conversion of x, w_qkv, w_o (dst regions contiguous in ws)
__global__ __launch_bounds__(256) void cvt_all(const float* __restrict__ x,
                                               const float* __restrict__ wq,
                                               const float* __restrict__ wo,
                                               u16* __restrict__ dst) {
  int i = blockIdx.x * 256 + threadIdx.x;
  const float* src; int off;
  if (i < 524288)      { src = x;  off = 0; }
  else if (i < 917504) { src = wq; off = 524288; }
  else                 { src = wo; off = 917504; }
  cvt8(&dst[(size_t)i * 8], &src[(size_t)(i - off) * 8]);
}

// f32x4 accumulator quad -> 4 bf16
__device__ __forceinline__ s4 cvt4(f32x4 v) {
  union { __bf16 b[4]; s4 s; } u;
  u.b[0] = (__bf16)v[0]; u.b[1] = (__bf16)v[1];
  u.b[2] = (__bf16)v[2]; u.b[3] = (__bf16)v[3];
  return u.s;
}

__device__ __forceinline__ f32x4 mfma16(s4 a, s4 b, f32x4 c) {
#if __has_builtin(__builtin_amdgcn_mfma_f32_16x16x16bf16_1k)
  return __builtin_amdgcn_mfma_f32_16x16x16bf16_1k(a, b, c, 0, 0, 0);
#else
  asm("v_mfma_f32_16x16x16_bf16 %0, %1, %2, %0" : "+v"(c) : "v"(a), "v"(b));
  return c;
#endif
}

// native 2^x
__device__ __forceinline__ float exp2fast(float x) {
#if __has_builtin(__builtin_amdgcn_exp2f)
  return __builtin_amdgcn_exp2f(x);
#else
  float r; asm("v_exp_f32 %0, %1" : "=v"(r) : "v"(x)); return r;
#endif
}

// async 16B global -> LDS (HW scatters lane i at ldsbase + i*16)
__device__ __forceinline__ void gl_lds(const u16* g, u16* ldsbase) {
  __builtin_amdgcn_global_load_lds(
      (const __attribute__((address_space(1))) void*)g,
      (__attribute__((address_space(3))) void*)ldsbase, 16, 0, 0);
}

// C[M,N] = A[M,K] * W[N,K]^T. A,W bf16; C fp32 (CF32) or bf16 ws.
// KV: k cols (1024..2047) -> qkv bf16 + outk fp32; v cols (>=2048) ->
//     outv fp32 + TRANSPOSED bf16 into vt (fused transpose_v).
// tile 128x128, BK=64, global_load_lds staging, XOR-swizzled linear LDS,
// bijective XCD-aware block swizzle (grid %8 == 0).
// T3-minimum 2-phase dbuf: stage(t+1) issued BEFORE compute(t), drained after
// -- stage latency hides under the MFMA compute phase.
// WAVES=8 (512 thr): 64x32 per wave, 64 KB dbuf -> 2 blocks/CU = 16 waves/CU.
template <bool CF32, bool KV, int WAVES>
__global__ __launch_bounds__(WAVES * 64) void gemm_bt(
    const u16* __restrict__ A, const u16* __restrict__ W,
    void* __restrict__ Cp, float* __restrict__ outk, float* __restrict__ outv,
    u16* __restrict__ vtp, int M, int N, int K) {
  constexpr int NJ = (WAVES == 4) ? 4 : 2;   // N-frags per wave
  constexpr int SI = 16 / WAVES;             // staging iters (8-row groups)
  __shared__ __align__(16) u16 As[2][128 * 64];
  __shared__ __align__(16) u16 Bs[2][128 * 64];
  const int tid  = threadIdx.x;
  const int bid  = blockIdx.y * gridDim.x + blockIdx.x;
  const int per  = (gridDim.x * gridDim.y) >> 3;
  const int swz  = (bid & 7) * per + (bid >> 3);
  const int n0   = (swz % gridDim.x) * 128;
  const int m0   = (swz / gridDim.x) * 128;
  const int lane = tid & 63;
  const int wave = tid >> 6;
  const int wm   = (WAVES == 4 ? (wave >> 1) : (wave >> 2)) * 64;
  const int wn   = (WAVES == 4 ? (wave & 1) * 64 : (wave & 3) * 32);
  const int l15  = lane & 15;
  const int quad = lane >> 4;
  const int srow = lane >> 3;   // row within 8-row stage group
  const int sc   = lane & 7;    // 16B chunk within row

  f32x4 acc[4][NJ];
#pragma unroll
  for (int i = 0; i < 4; i++)
#pragma unroll
    for (int j = 0; j < NJ; j++) acc[i][j] = (f32x4){0.f, 0.f, 0.f, 0.f};

  auto stage = [&](int d, int k0) {
#pragma unroll
    for (int i = 0; i < SI; i++) {
      int r0  = (i * WAVES + wave) * 8;
      int row = r0 + srow;
      int gc  = (sc ^ (row & 7)) << 3;  // pre-swizzled source column (u16)
      gl_lds(&A[(size_t)(m0 + row) * K + k0 + gc], &As[d][r0 * 64]);
      gl_lds(&W[(size_t)(n0 + row) * K + k0 + gc], &Bs[d][r0 * 64]);
    }
  };

  stage(0, 0);
  asm volatile("s_waitcnt vmcnt(0)" ::: "memory");
  __builtin_amdgcn_s_barrier();
  __builtin_amdgcn_sched_barrier(0);

  const int NT = K >> 6;
  int cur = 0;
  for (int t = 0; t < NT; t++) {
    if (t + 1 < NT) stage(cur ^ 1, (t + 1) * 64);  // in flight under compute
#pragma unroll
    for (int kk = 0; kk < 64; kk += 32) {
      bf16x8 af[4], bfr[NJ];
#pragma unroll
      for (int i = 0; i < 4; i++) {
        int arow = wm + i * 16 + l15;
        af[i] = *(const bf16x8*)((const char*)&As[cur][0] + arow * 128 +
                                 ((((kk >> 3) + quad) ^ (arow & 7)) << 4));
      }
#pragma unroll
      for (int j = 0; j < NJ; j++) {
        int brow = wn + j * 16 + l15;
        bfr[j] = *(const bf16x8*)((const char*)&Bs[cur][0] + brow * 128 +
                                  ((((kk >> 3) + quad) ^ (brow & 7)) << 4));
      }
#pragma unroll
      for (int i = 0; i < 4; i++)
#pragma unroll
        for (int j = 0; j < NJ; j++)
          acc[i][j] = __builtin_amdgcn_mfma_f32_16x16x32_bf16(af[i], bfr[j], acc[i][j], 0, 0, 0);
    }
    asm volatile("s_waitcnt vmcnt(0)" ::: "memory");
    __builtin_amdgcn_s_barrier();
    __builtin_amdgcn_sched_barrier(0);
    cur ^= 1;
  }
#pragma unroll
  for (int i = 0; i < 4; i++)
#pragma unroll
    for (int j = 0; j < NJ; j++) {
      const int row0 = m0 + wm + i * 16 + quad * 4;  // 4 consecutive rows
      const int col  = n0 + wn + j * 16 + l15;
      if constexpr (CF32) {
#pragma unroll
        for (int r = 0; r < 4; r++)
          ((float*)Cp)[(size_t)(row0 + r) * N + col] = acc[i][j][r];
      } else if (KV && col >= 2048) {
        // v: fp32 output + transposed bf16 into vt (4 consecutive t -> 8B)
        const int hd = col - 2048;
        const int b_ = row0 >> 11, t_ = row0 & 2047;
        uint2 pk;
        pk.x = pk2bf(acc[i][j][0], acc[i][j][1]);
        pk.y = pk2bf(acc[i][j][2], acc[i][j][3]);
        *(uint2*)&vtp[((size_t)(b_ * NH + (hd >> 6)) * 64 + (hd & 63)) * 2048 + t_] = pk;
#pragma unroll
        for (int r = 0; r < 4; r++)
          outv[(size_t)(row0 + r) * 1024 + hd] = acc[i][j][r];
      } else {
#pragma unroll
        for (int r = 0; r < 4; r++) {
          float v = acc[i][j][r];
          ((u16*)Cp)[(size_t)(row0 + r) * N + col] = f2bf(v);
          if constexpr (KV) {
            if (col >= 1024) outk[(size_t)(row0 + r) * 1024 + (col - 1024)] = v;
          }
        }
      }
    }
}

// Flash-style causal attention, swapped QK^T (S^T = mfma(K,Q)).
// ONE 64-row q-tile per block (grid 32x32 = 1024 blocks -> 4 blocks/CU).
// 2-buffer K/V LDS pipeline (32 KB/block), one barrier/step, stage(s+1)
// issued right after the barrier.  Constant-sum balanced, per-head bijective
// q-tile assignment: co-resident quads {by, by+8, by+16, by+24} sum to 66.
// (Round-9 winner, 56.4 us, unchanged.)
__global__ __launch_bounds__(256) void attn(const u16* __restrict__ qkv,
                                            const u16* __restrict__ vt,
                                            u16* __restrict__ o) {
  __shared__ __align__(16) u16 Ks[2][64 * 64];
  __shared__ __align__(16) u16 Vts[2][64 * 64];

  const int tid  = threadIdx.x;
  const int bx   = blockIdx.x;          // 0..31
  const int by   = blockIdx.y;          // bh = b*16+h, 0..31
  const int b    = by >> 4, h = by & 15;
  const int lane = tid & 63, wave = tid >> 6;
  const int l15  = lane & 15, quad = lane >> 4;
  const int srow = lane >> 3, sc = lane & 7;
  const size_t qbase = (size_t)b * T_SEQ * 3072;
  const size_t vbase = (size_t)(b * NH + h) * 64 * 2048;
  const float C = 0.1803368801f;        // 0.125 * log2(e)

  // constant-sum balanced, per-head bijective q-tile assignment
  const int u  = (bx + (by & 7) * 5) & 31;
  const int c  = by >> 3;               // 0..3: co-resident quad index
  const int v_ = (u + ((c >> 1) << 4)) & 31;
  const int qt = (c & 1) ? (31 - v_) : v_;
  const int steps = qt + 1;

  const int wq0  = qt * 64 + wave * 16;
  const int qrow = wq0 + l15;

  // Q fragments (B-operand: n=l15 -> q row), loaded once from global
  const u16* qp = &qkv[qbase + (size_t)qrow * 3072 + h * 64];
  const bf16x8 qf0 = *(const bf16x8*)&qp[quad * 8];
  const bf16x8 qf1 = *(const bf16x8*)&qp[32 + quad * 8];

  f32x4 acc_o[4];
#pragma unroll
  for (int n = 0; n < 4; n++) acc_o[n] = (f32x4){0.f, 0.f, 0.f, 0.f};
  float m2run = -1e30f, lrun = 0.f;

  // async stage of k-tile kt into buffer buf: 4 gl_lds per wave
  auto stage = [&](int buf, int kt) {
    const int k0 = kt * 64;
#pragma unroll
    for (int i = 0; i < 2; i++) {
      int r0  = (wave * 2 + i) * 8;
      int row = r0 + srow;
      int gc  = (sc ^ (row & 7)) << 3;
      gl_lds(&qkv[qbase + (size_t)(k0 + row) * 3072 + 1024 + h * 64 + gc], &Ks[buf][r0 * 64]);
      gl_lds(&vt[vbase + (size_t)row * 2048 + k0 + gc], &Vts[buf][r0 * 64]);
    }
  };

  stage(0, 0);

  for (int s = 0; s < steps; s++) {
    const int cur = s & 1;
    asm volatile("s_waitcnt vmcnt(0)" ::: "memory");
    __builtin_amdgcn_s_barrier();
    __builtin_amdgcn_sched_barrier(0);

    if (s + 1 < steps) stage(cur ^ 1, s + 1);

    const int k0 = s * 64;

    // S^T[j]: row (quad*4+r) = k_local, col l15 = q  (swizzled Ks reads)
    f32x4 sacc[4];
#pragma unroll
    for (int j = 0; j < 4; j++) sacc[j] = (f32x4){0.f, 0.f, 0.f, 0.f};
    __builtin_amdgcn_s_setprio(1);
#pragma unroll
    for (int j = 0; j < 4; j++) {
      int krow = j * 16 + l15;
      const char* kb = (const char*)&Ks[cur][0] + krow * 128;
      bf16x8 kfa = *(const bf16x8*)(kb + ((quad ^ (krow & 7)) << 4));
      bf16x8 kfb = *(const bf16x8*)(kb + (((4 + quad) ^ (krow & 7)) << 4));
      sacc[j] = __builtin_amdgcn_mfma_f32_16x16x32_bf16(kfa, qf0, sacc[j], 0, 0, 0);
      sacc[j] = __builtin_amdgcn_mfma_f32_16x16x32_bf16(kfb, qf1, sacc[j], 0, 0, 0);
    }
    __builtin_amdgcn_s_setprio(0);

    if (s == qt) {  // diagonal tile: causal mask on raw scores
#pragma unroll
      for (int j = 0; j < 4; j++)
#pragma unroll
        for (int r = 0; r < 4; r++) {
          int k = k0 + j * 16 + quad * 4 + r;
          if (k > qrow) sacc[j][r] = -1e30f;
        }
    }

    // row max, tree-shaped
    float mj[4];
#pragma unroll
    for (int j = 0; j < 4; j++)
      mj[j] = fmaxf(fmaxf(sacc[j][0], sacc[j][1]), fmaxf(sacc[j][2], sacc[j][3]));
    float mx = fmaxf(fmaxf(mj[0], mj[1]), fmaxf(mj[2], mj[3]));
    mx = fmaxf(mx, __shfl_xor(mx, 16));
    mx = fmaxf(mx, __shfl_xor(mx, 32));
    const float m2x = mx * C;

    // defer-max: only rescale when the max grew by > 8 (log2 domain)
    if (!__all(m2x <= m2run + 8.0f)) {
      const float m2new = fmaxf(m2run, m2x);
      const float alpha = exp2fast(m2run - m2new);
      lrun *= alpha;
      m2run = m2new;
#pragma unroll
      for (int r = 0; r < 4; r++) {
        float ar = __shfl(alpha, quad * 4 + r);
#pragma unroll
        for (int n = 0; n < 4; n++) acc_o[n][r] *= ar;
      }
    }

    // p = exp2(s*C - m2run); tree sum
    const float nm = m2run;
    float ts[4];
#pragma unroll
    for (int j = 0; j < 4; j++) {
#pragma unroll
      for (int r = 0; r < 4; r++) sacc[j][r] = exp2fast(fmaf(sacc[j][r], C, -nm));
      ts[j] = (sacc[j][0] + sacc[j][1]) + (sacc[j][2] + sacc[j][3]);
    }
    float sum = (ts[0] + ts[1]) + (ts[2] + ts[3]);
    sum += __shfl_xor(sum, 16);
    sum += __shfl_xor(sum, 32);
    lrun += sum;

    // P -> bf16 A-frags (m=l15 -> q, k = quad*4+e), in-register
    s4 pa[4];
#pragma unroll
    for (int j = 0; j < 4; j++) pa[j] = cvt4(sacc[j]);

    // PV: B-frag = V^T[d = n*16+l15][k0 + j*16+quad*4 ..+3], swizzled b64
    __builtin_amdgcn_s_setprio(1);
#pragma unroll
    for (int j = 0; j < 4; j++)
#pragma unroll
      for (int n = 0; n < 4; n++) {
        int vrow = n * 16 + l15;
        int ch = (j * 2 + (quad >> 1)) ^ (vrow & 7);
        const s4 vf = *(const s4*)((const char*)&Vts[cur][0] + vrow * 128 +
                                   (ch << 4) + ((quad & 1) << 3));
        acc_o[n] = mfma16(pa[j], vf, acc_o[n]);
      }
    __builtin_amdgcn_s_setprio(0);
  }

  const float linv = 1.0f / lrun;
#pragma unroll
  for (int r = 0; r < 4; r++) {
    const float lr = __shfl(linv, quad * 4 + r);
    const int row = wq0 + quad * 4 + r;
#pragma unroll
    for (int n = 0; n < 4; n++)
      o[(size_t)(b * T_SEQ + row) * 1024 + h * 64 + n * 16 + l15] =
          f2bf(acc_o[n][r] * lr);
  }
}

extern "C" void kernel_launch(void* const* d_in, const int* in_sizes, int n_in,
                              void* d_out, int out_size, void* d_ws, size_t ws_size,
                              hipStream_t stream) {
  const float* x     = (const float*)d_in[0];   // (2,2048,1024) fp32
  const float* w_qkv = (const float*)d_in[1];   // (3072,1024)   fp32
  const float* w_o   = (const float*)d_in[2];   // (1024,1024)   fp32
  float* out  = (float*)d_out;                  // fp32 (4096,1024)
  float* outk = out + (size_t)4194304;
  float* outv = out + (size_t)8388608;

  u16* qkv = (u16*)d_ws;                        // 4096*3072
  u16* vt  = qkv + (size_t)4096 * 3072;         // 32*64*2048
  u16* ao  = vt  + (size_t)4194304;             // 4096*1024
  u16* xb  = ao  + (size_t)4194304;             // 4096*1024
  u16* wqb = xb  + (size_t)4194304;             // 3072*1024
  u16* wob = wqb + (size_t)3145728;             // 1024*1024

  // 0. fused fp32 -> bf16 conversion (xb, wqb, wob contiguous)
  cvt_all<<<4096, 256, 0, stream>>>(x, w_qkv, w_o, xb);

  // 1. qkv(bf16 ws) = xb @ wqb^T; k -> qkv+outk; v -> outv + vt (fused
  //    transpose).  8 waves / 512 thr: 16 waves/CU (was 8).
  gemm_bt<false, true, 8><<<dim3(24, 32), 512, 0, stream>>>(
      xb, wqb, qkv, outk, outv, vt, 4096, 3072, 1024);
  // 2. flash attention -> ao (bf16 ws): 1 tile/block, 1024 blocks, 2-buf pipe
  attn<<<dim3(32, 32), 256, 0, stream>>>(qkv, vt, ao);
  // 3. out(fp32) = ao @ wob^T: 8 waves on 128x128 tile
  gemm_bt<true, false, 8><<<dim3(8, 32), 512, 0, stream>>>(
      ao, wob, out, nullptr, nullptr, nullptr, 4096, 1024, 1024);
}

// Round 12
// 192.944 us; speedup vs baseline: 1.3293x; 1.0152x over previous
//
#include <hip/hip_runtime.h>
#include <cstdint>

typedef unsigned short u16;
typedef __bf16 bf16x8 __attribute__((ext_vector_type(8)));
typedef float f32x4 __attribute__((ext_vector_type(4)));
typedef short s4 __attribute__((ext_vector_type(4)));

#define T_SEQ 2048
#define NH 16

// RTNE float -> bf16 bits
__device__ __forceinline__ u16 f2bf(float f) {
  union { float f; uint32_t u; } x; x.f = f;
  uint32_t r = (x.u + 0x7fffu + ((x.u >> 16) & 1u)) >> 16;
  return (u16)r;
}

// pack two floats -> two bf16 (RTNE)
__device__ __forceinline__ uint32_t pk2bf(float a, float b) {
  union { float f; uint32_t u; } x, y; x.f = a; y.f = b;
  uint32_t lo = (x.u + 0x7fffu + ((x.u >> 16) & 1u)) >> 16;
  uint32_t hi = (y.u + 0x7fffu + ((y.u >> 16) & 1u)) >> 16;
  return lo | (hi << 16);
}

// 8 fp32 -> 8 bf16 (one uint4 store)
__device__ __forceinline__ void cvt8(u16* dst, const float* src) {
  float4 a = *(const float4*)src;
  float4 b = *(const float4*)(src + 4);
  uint4 o;
  o.x = pk2bf(a.x, a.y); o.y = pk2bf(a.z, a.w);
  o.z = pk2bf(b.x, b.y); o.w = pk2bf(b.z, b.w);
  *(uint4*)dst = o;
}

// fused fp32 -> bf16 conversion of x, w_qkv, w_o (dst regions contiguous in ws)
__global__ __launch_bounds__(256) void cvt_all(const float* __restrict__ x,
                                               const float* __restrict__ wq,
                                               const float* __restrict__ wo,
                                               u16* __restrict__ dst) {
  int i = blockIdx.x * 256 + threadIdx.x;
  const float* src; int off;
  if (i < 524288)      { src = x;  off = 0; }
  else if (i < 917504) { src = wq; off = 524288; }
  else                 { src = wo; off = 917504; }
  cvt8(&dst[(size_t)i * 8], &src[(size_t)(i - off) * 8]);
}

// f32x4 accumulator quad -> 4 bf16
__device__ __forceinline__ s4 cvt4(f32x4 v) {
  union { __bf16 b[4]; s4 s; } u;
  u.b[0] = (__bf16)v[0]; u.b[1] = (__bf16)v[1];
  u.b[2] = (__bf16)v[2]; u.b[3] = (__bf16)v[3];
  return u.s;
}

__device__ __forceinline__ f32x4 mfma16(s4 a, s4 b, f32x4 c) {
#if __has_builtin(__builtin_amdgcn_mfma_f32_16x16x16bf16_1k)
  return __builtin_amdgcn_mfma_f32_16x16x16bf16_1k(a, b, c, 0, 0, 0);
#else
  asm("v_mfma_f32_16x16x16_bf16 %0, %1, %2, %0" : "+v"(c) : "v"(a), "v"(b));
  return c;
#endif
}

// native 2^x
__device__ __forceinline__ float exp2fast(float x) {
#if __has_builtin(__builtin_amdgcn_exp2f)
  return __builtin_amdgcn_exp2f(x);
#else
  float r; asm("v_exp_f32 %0, %1" : "=v"(r) : "v"(x)); return r;
#endif
}

// async 16B global -> LDS (HW scatters lane i at ldsbase + i*16)
__device__ __forceinline__ void gl_lds(const u16* g, u16* ldsbase) {
  __builtin_amdgcn_global_load_lds(
      (const __attribute__((address_space(1))) void*)g,
      (__attribute__((address_space(3))) void*)ldsbase, 16, 0, 0);
}

// C[M,N] = A[M,K] * W[N,K]^T. A,W bf16; C fp32 (CF32) or bf16 ws.
// KV: k cols (1024..2047) -> qkv bf16 + outk fp32; v cols (>=2048) ->
//     outv fp32 + TRANSPOSED bf16 into vt (fused transpose_v).
// tile BMx128, BK=64, 512 threads = 8 waves, each (BM/2)x32.
// global_load_lds staging, XOR-swizzled linear LDS, bijective XCD swizzle.
// T3-minimum 2-phase dbuf: stage(t+1) issued BEFORE compute(t), drained after.
// BM=128: 64 KB dbuf, 2 blocks/CU.  BM=64: 48 KB dbuf, 2-3 blocks/CU --
// doubles gemm2's grid (256 -> 512 blocks), fixing its 1-block/CU starvation.
template <bool CF32, bool KV, int BM>
__global__ __launch_bounds__(512) void gemm_bt(
    const u16* __restrict__ A, const u16* __restrict__ W,
    void* __restrict__ Cp, float* __restrict__ outk, float* __restrict__ outv,
    u16* __restrict__ vtp, int M, int N, int K) {
  constexpr int WM = BM / 2;            // wave m-extent
  constexpr int MI = WM / 16;           // m-frags per wave
  constexpr int NJ = 2;                 // n-frags per wave (32 cols)
  __shared__ __align__(16) u16 As[2][BM * 64];
  __shared__ __align__(16) u16 Bs[2][128 * 64];
  const int tid  = threadIdx.x;
  const int bid  = blockIdx.y * gridDim.x + blockIdx.x;
  const int per  = (gridDim.x * gridDim.y) >> 3;
  const int swz  = (bid & 7) * per + (bid >> 3);
  const int n0   = (swz % gridDim.x) * 128;
  const int m0   = (swz / gridDim.x) * BM;
  const int lane = tid & 63;
  const int wave = tid >> 6;            // 0..7
  const int wm   = (wave >> 2) * WM;
  const int wn   = (wave & 3) * 32;
  const int l15  = lane & 15;
  const int quad = lane >> 4;
  const int srow = lane >> 3;   // row within 8-row stage group
  const int sc   = lane & 7;    // 16B chunk within row

  f32x4 acc[MI][NJ];
#pragma unroll
  for (int i = 0; i < MI; i++)
#pragma unroll
    for (int j = 0; j < NJ; j++) acc[i][j] = (f32x4){0.f, 0.f, 0.f, 0.f};

  auto stage = [&](int d, int k0) {
#pragma unroll
    for (int i = 0; i < BM / 64; i++) {     // A: BM/8 groups over 8 waves
      int r0  = (i * 8 + wave) * 8;
      int row = r0 + srow;
      int gc  = (sc ^ (row & 7)) << 3;      // pre-swizzled source column
      gl_lds(&A[(size_t)(m0 + row) * K + k0 + gc], &As[d][r0 * 64]);
    }
#pragma unroll
    for (int i = 0; i < 2; i++) {           // B: 16 groups over 8 waves
      int r0  = (i * 8 + wave) * 8;
      int row = r0 + srow;
      int gc  = (sc ^ (row & 7)) << 3;
      gl_lds(&W[(size_t)(n0 + row) * K + k0 + gc], &Bs[d][r0 * 64]);
    }
  };

  stage(0, 0);
  asm volatile("s_waitcnt vmcnt(0)" ::: "memory");
  __builtin_amdgcn_s_barrier();
  __builtin_amdgcn_sched_barrier(0);

  const int NT = K >> 6;
  int cur = 0;
  for (int t = 0; t < NT; t++) {
    if (t + 1 < NT) stage(cur ^ 1, (t + 1) * 64);  // in flight under compute
#pragma unroll
    for (int kk = 0; kk < 64; kk += 32) {
      bf16x8 af[MI], bfr[NJ];
#pragma unroll
      for (int i = 0; i < MI; i++) {
        int arow = wm + i * 16 + l15;
        af[i] = *(const bf16x8*)((const char*)&As[cur][0] + arow * 128 +
                                 ((((kk >> 3) + quad) ^ (arow & 7)) << 4));
      }
#pragma unroll
      for (int j = 0; j < NJ; j++) {
        int brow = wn + j * 16 + l15;
        bfr[j] = *(const bf16x8*)((const char*)&Bs[cur][0] + brow * 128 +
                                  ((((kk >> 3) + quad) ^ (brow & 7)) << 4));
      }
#pragma unroll
      for (int i = 0; i < MI; i++)
#pragma unroll
        for (int j = 0; j < NJ; j++)
          acc[i][j] = __builtin_amdgcn_mfma_f32_16x16x32_bf16(af[i], bfr[j], acc[i][j], 0, 0, 0);
    }
    asm volatile("s_waitcnt vmcnt(0)" ::: "memory");
    __builtin_amdgcn_s_barrier();
    __builtin_amdgcn_sched_barrier(0);
    cur ^= 1;
  }
#pragma unroll
  for (int i = 0; i < MI; i++)
#pragma unroll
    for (int j = 0; j < NJ; j++) {
      const int row0 = m0 + wm + i * 16 + quad * 4;  // 4 consecutive rows
      const int col  = n0 + wn + j * 16 + l15;
      if constexpr (CF32) {
#pragma unroll
        for (int r = 0; r < 4; r++)
          ((float*)Cp)[(size_t)(row0 + r) * N + col] = acc[i][j][r];
      } else if (KV && col >= 2048) {
        // v: fp32 output + transposed bf16 into vt (4 consecutive t -> 8B)
        const int hd = col - 2048;
        const int b_ = row0 >> 11, t_ = row0 & 2047;
        uint2 pk;
        pk.x = pk2bf(acc[i][j][0], acc[i][j][1]);
        pk.y = pk2bf(acc[i][j][2], acc[i][j][3]);
        *(uint2*)&vtp[((size_t)(b_ * NH + (hd >> 6)) * 64 + (hd & 63)) * 2048 + t_] = pk;
#pragma unroll
        for (int r = 0; r < 4; r++)
          outv[(size_t)(row0 + r) * 1024 + hd] = acc[i][j][r];
      } else {
#pragma unroll
        for (int r = 0; r < 4; r++) {
          float v = acc[i][j][r];
          ((u16*)Cp)[(size_t)(row0 + r) * N + col] = f2bf(v);
          if constexpr (KV) {
            if (col >= 1024) outk[(size_t)(row0 + r) * 1024 + (col - 1024)] = v;
          }
        }
      }
    }
}

// Flash-style causal attention, swapped QK^T (S^T = mfma(K,Q)).
// ONE 64-row q-tile per block (grid 32x32 = 1024 blocks -> 4 blocks/CU).
// 2-buffer K/V LDS pipeline (32 KB/block), one barrier/step, stage(s+1)
// issued right after the barrier.  Constant-sum balanced, per-head bijective
// q-tile assignment: co-resident quads {by, by+8, by+16, by+24} sum to 66.
// (Round-9 winner, 56.4 us, unchanged.)
__global__ __launch_bounds__(256) void attn(const u16* __restrict__ qkv,
                                            const u16* __restrict__ vt,
                                            u16* __restrict__ o) {
  __shared__ __align__(16) u16 Ks[2][64 * 64];
  __shared__ __align__(16) u16 Vts[2][64 * 64];

  const int tid  = threadIdx.x;
  const int bx   = blockIdx.x;          // 0..31
  const int by   = blockIdx.y;          // bh = b*16+h, 0..31
  const int b    = by >> 4, h = by & 15;
  const int lane = tid & 63, wave = tid >> 6;
  const int l15  = lane & 15, quad = lane >> 4;
  const int srow = lane >> 3, sc = lane & 7;
  const size_t qbase = (size_t)b * T_SEQ * 3072;
  const size_t vbase = (size_t)(b * NH + h) * 64 * 2048;
  const float C = 0.1803368801f;        // 0.125 * log2(e)

  // constant-sum balanced, per-head bijective q-tile assignment
  const int u  = (bx + (by & 7) * 5) & 31;
  const int c  = by >> 3;               // 0..3: co-resident quad index
  const int v_ = (u + ((c >> 1) << 4)) & 31;
  const int qt = (c & 1) ? (31 - v_) : v_;
  const int steps = qt + 1;

  const int wq0  = qt * 64 + wave * 16;
  const int qrow = wq0 + l15;

  // Q fragments (B-operand: n=l15 -> q row), loaded once from global
  const u16* qp = &qkv[qbase + (size_t)qrow * 3072 + h * 64];
  const bf16x8 qf0 = *(const bf16x8*)&qp[quad * 8];
  const bf16x8 qf1 = *(const bf16x8*)&qp[32 + quad * 8];

  f32x4 acc_o[4];
#pragma unroll
  for (int n = 0; n < 4; n++) acc_o[n] = (f32x4){0.f, 0.f, 0.f, 0.f};
  float m2run = -1e30f, lrun = 0.f;

  // async stage of k-tile kt into buffer buf: 4 gl_lds per wave
  auto stage = [&](int buf, int kt) {
    const int k0 = kt * 64;
#pragma unroll
    for (int i = 0; i < 2; i++) {
      int r0  = (wave * 2 + i) * 8;
      int row = r0 + srow;
      int gc  = (sc ^ (row & 7)) << 3;
      gl_lds(&qkv[qbase + (size_t)(k0 + row) * 3072 + 1024 + h * 64 + gc], &Ks[buf][r0 * 64]);
      gl_lds(&vt[vbase + (size_t)row * 2048 + k0 + gc], &Vts[buf][r0 * 64]);
    }
  };

  stage(0, 0);

  for (int s = 0; s < steps; s++) {
    const int cur = s & 1;
    asm volatile("s_waitcnt vmcnt(0)" ::: "memory");
    __builtin_amdgcn_s_barrier();
    __builtin_amdgcn_sched_barrier(0);

    if (s + 1 < steps) stage(cur ^ 1, s + 1);

    const int k0 = s * 64;

    // S^T[j]: row (quad*4+r) = k_local, col l15 = q  (swizzled Ks reads)
    f32x4 sacc[4];
#pragma unroll
    for (int j = 0; j < 4; j++) sacc[j] = (f32x4){0.f, 0.f, 0.f, 0.f};
    __builtin_amdgcn_s_setprio(1);
#pragma unroll
    for (int j = 0; j < 4; j++) {
      int krow = j * 16 + l15;
      const char* kb = (const char*)&Ks[cur][0] + krow * 128;
      bf16x8 kfa = *(const bf16x8*)(kb + ((quad ^ (krow & 7)) << 4));
      bf16x8 kfb = *(const bf16x8*)(kb + (((4 + quad) ^ (krow & 7)) << 4));
      sacc[j] = __builtin_amdgcn_mfma_f32_16x16x32_bf16(kfa, qf0, sacc[j], 0, 0, 0);
      sacc[j] = __builtin_amdgcn_mfma_f32_16x16x32_bf16(kfb, qf1, sacc[j], 0, 0, 0);
    }
    __builtin_amdgcn_s_setprio(0);

    if (s == qt) {  // diagonal tile: causal mask on raw scores
#pragma unroll
      for (int j = 0; j < 4; j++)
#pragma unroll
        for (int r = 0; r < 4; r++) {
          int k = k0 + j * 16 + quad * 4 + r;
          if (k > qrow) sacc[j][r] = -1e30f;
        }
    }

    // row max, tree-shaped
    float mj[4];
#pragma unroll
    for (int j = 0; j < 4; j++)
      mj[j] = fmaxf(fmaxf(sacc[j][0], sacc[j][1]), fmaxf(sacc[j][2], sacc[j][3]));
    float mx = fmaxf(fmaxf(mj[0], mj[1]), fmaxf(mj[2], mj[3]));
    mx = fmaxf(mx, __shfl_xor(mx, 16));
    mx = fmaxf(mx, __shfl_xor(mx, 32));
    const float m2x = mx * C;

    // defer-max: only rescale when the max grew by > 8 (log2 domain)
    if (!__all(m2x <= m2run + 8.0f)) {
      const float m2new = fmaxf(m2run, m2x);
      const float alpha = exp2fast(m2run - m2new);
      lrun *= alpha;
      m2run = m2new;
#pragma unroll
      for (int r = 0; r < 4; r++) {
        float ar = __shfl(alpha, quad * 4 + r);
#pragma unroll
        for (int n = 0; n < 4; n++) acc_o[n][r] *= ar;
      }
    }

    // p = exp2(s*C - m2run); tree sum
    const float nm = m2run;
    float ts[4];
#pragma unroll
    for (int j = 0; j < 4; j++) {
#pragma unroll
      for (int r = 0; r < 4; r++) sacc[j][r] = exp2fast(fmaf(sacc[j][r], C, -nm));
      ts[j] = (sacc[j][0] + sacc[j][1]) + (sacc[j][2] + sacc[j][3]);
    }
    float sum = (ts[0] + ts[1]) + (ts[2] + ts[3]);
    sum += __shfl_xor(sum, 16);
    sum += __shfl_xor(sum, 32);
    lrun += sum;

    // P -> bf16 A-frags (m=l15 -> q, k = quad*4+e), in-register
    s4 pa[4];
#pragma unroll
    for (int j = 0; j < 4; j++) pa[j] = cvt4(sacc[j]);

    // PV: B-frag = V^T[d = n*16+l15][k0 + j*16+quad*4 ..+3], swizzled b64
    __builtin_amdgcn_s_setprio(1);
#pragma unroll
    for (int j = 0; j < 4; j++)
#pragma unroll
      for (int n = 0; n < 4; n++) {
        int vrow = n * 16 + l15;
        int ch = (j * 2 + (quad >> 1)) ^ (vrow & 7);
        const s4 vf = *(const s4*)((const char*)&Vts[cur][0] + vrow * 128 +
                                   (ch << 4) + ((quad & 1) << 3));
        acc_o[n] = mfma16(pa[j], vf, acc_o[n]);
      }
    __builtin_amdgcn_s_setprio(0);
  }

  const float linv = 1.0f / lrun;
#pragma unroll
  for (int r = 0; r < 4; r++) {
    const float lr = __shfl(linv, quad * 4 + r);
    const int row = wq0 + quad * 4 + r;
#pragma unroll
    for (int n = 0; n < 4; n++)
      o[(size_t)(b * T_SEQ + row) * 1024 + h * 64 + n * 16 + l15] =
          f2bf(acc_o[n][r] * lr);
  }
}

extern "C" void kernel_launch(void* const* d_in, const int* in_sizes, int n_in,
                              void* d_out, int out_size, void* d_ws, size_t ws_size,
                              hipStream_t stream) {
  const float* x     = (const float*)d_in[0];   // (2,2048,1024) fp32
  const float* w_qkv = (const float*)d_in[1];   // (3072,1024)   fp32
  const float* w_o   = (const float*)d_in[2];   // (1024,1024)   fp32
  float* out  = (float*)d_out;                  // fp32 (4096,1024)
  float* outk = out + (size_t)4194304;
  float* outv = out + (size_t)8388608;

  u16* qkv = (u16*)d_ws;                        // 4096*3072
  u16* vt  = qkv + (size_t)4096 * 3072;         // 32*64*2048
  u16* ao  = vt  + (size_t)4194304;             // 4096*1024
  u16* xb  = ao  + (size_t)4194304;             // 4096*1024
  u16* wqb = xb  + (size_t)4194304;             // 3072*1024
  u16* wob = wqb + (size_t)3145728;             // 1024*1024

  // 0. fused fp32 -> bf16 conversion (xb, wqb, wob contiguous)
  cvt_all<<<4096, 256, 0, stream>>>(x, w_qkv, w_o, xb);

  // 1. qkv(bf16 ws) = xb @ wqb^T; k -> qkv+outk; v -> outv + vt (fused
  //    transpose).  128x128 tile, 8 waves, 16 waves/CU.
  gemm_bt<false, true, 128><<<dim3(24, 32), 512, 0, stream>>>(
      xb, wqb, qkv, outk, outv, vt, 4096, 3072, 1024);
  // 2. flash attention -> ao (bf16 ws): 1 tile/block, 1024 blocks, 2-buf pipe
  attn<<<dim3(32, 32), 256, 0, stream>>>(qkv, vt, ao);
  // 3. out(fp32) = ao @ wob^T: 64x128 tile -> 512 blocks (2/CU, was 1/CU)
  gemm_bt<true, false, 64><<<dim3(8, 64), 512, 0, stream>>>(
      ao, wob, out, nullptr, nullptr, nullptr, 4096, 1024, 1024);
}